// Round 4
// baseline (375.506 us; speedup 1.0000x reference)
//
#include <hip/hip_runtime.h>

#define K_TOP 5000
#define NBIN 2048
#define CAND_LDS 1024
#define NB_BUCKET 4096
#define TARGET_SAMPLED 94u   // ~12000 true candidates at 1/128 sampling

// ---- order-preserving float<->key mapping -------------------------------
__device__ __forceinline__ unsigned f2key(float f) {
    unsigned u = __float_as_uint(f);
    return (u & 0x80000000u) ? ~u : (u | 0x80000000u);
}
__device__ __forceinline__ float key2f(unsigned k) {
    unsigned u = (k & 0x80000000u) ? (k ^ 0x80000000u) : ~k;
    return __uint_as_float(u);
}

// ---- sampled histogram (1/128) + fused last-block threshold pick --------
// ctrl: [0]=candCount [1]=L [4]=done-counter
__global__ __launch_bounds__(256) void k_sample(const float4* __restrict__ x4, long n4,
                                                unsigned* __restrict__ hist,
                                                unsigned* __restrict__ ctrl) {
    __shared__ unsigned lh[NBIN];
    __shared__ unsigned gs[64];
    __shared__ unsigned lastFlag;
    for (int i = threadIdx.x; i < NBIN; i += 256) lh[i] = 0;
    __syncthreads();
    int wave = threadIdx.x >> 6;
    int lane = threadIdx.x & 63;
    long gw = (long)blockIdx.x * 4 + wave;
    long totW = (long)gridDim.x * 4;
    long nChunk = (n4 + 8191) / 8192;
    for (long c = gw; c < nChunk; c += totW) {
        long i = c * 8192 + lane;
        if (i < n4) {
            float4 v = x4[i];
            atomicAdd(&lh[f2key(v.x) >> 21], 1u);
            atomicAdd(&lh[f2key(v.y) >> 21], 1u);
            atomicAdd(&lh[f2key(v.z) >> 21], 1u);
            atomicAdd(&lh[f2key(v.w) >> 21], 1u);
        }
    }
    __syncthreads();
    for (int i = threadIdx.x; i < NBIN; i += 256) {
        unsigned c = lh[i];
        if (c) atomicAdd(&hist[i], c);
    }
    // ---- last block computes conservative threshold L (saves a launch) ----
    __threadfence();
    if (threadIdx.x == 0)
        lastFlag = (atomicAdd(&ctrl[4], 1u) == gridDim.x - 1) ? 1u : 0u;
    __syncthreads();
    if (!lastFlag) return;
    __threadfence();
    for (int i = threadIdx.x; i < NBIN; i += 256)
        lh[i] = __hip_atomic_load(&hist[i], __ATOMIC_RELAXED, __HIP_MEMORY_SCOPE_AGENT);
    __syncthreads();
    int t = threadIdx.x;
    if (t < 64) {
        unsigned s = 0;
        for (int j = 0; j < 32; j++) s += lh[t * 32 + j];
        gs[t] = s;
    }
    __syncthreads();
    if (t == 0) {
        unsigned cum = 0;
        int g = 63;
        for (; g > 0; g--) { if (cum + gs[g] >= TARGET_SAMPLED) break; cum += gs[g]; }
        int b = g * 32 + 31;
        for (; b > g * 32; b--) { if (cum + lh[b] >= TARGET_SAMPLED) break; cum += lh[b]; }
        ctrl[1] = ((unsigned)b) << 21;
    }
}

// ---- full pass: compact candidates (key >= L), LDS-staged ---------------
// 8x float4 per thread per tile: 128 B in flight/thread for latency hiding.
__global__ __launch_bounds__(256) void k_compact(const float4* __restrict__ x4, long n4,
                                                 long n, const float* __restrict__ x,
                                                 unsigned* __restrict__ ctrl,
                                                 unsigned* __restrict__ candKey,
                                                 unsigned* __restrict__ candIdx,
                                                 unsigned capC) {
    __shared__ unsigned sKey[CAND_LDS], sIdx[CAND_LDS];
    __shared__ unsigned sCnt, sBase;
    if (threadIdx.x == 0) sCnt = 0;
    __syncthreads();
    unsigned L = ctrl[1];
    unsigned* candCount = &ctrl[0];

    // tail (n % 4) handled by block 0
    int tail = (int)(n & 3);
    if (blockIdx.x == 0 && threadIdx.x < tail) {
        unsigned k = f2key(x[n4 * 4 + threadIdx.x]);
        if (k >= L) {
            unsigned p = atomicAdd(&sCnt, 1u);
            if (p < CAND_LDS) { sKey[p] = k; sIdx[p] = (unsigned)(n4 * 4 + threadIdx.x); }
            else {
                unsigned q = atomicAdd(candCount, 1u);
                if (q < capC) { candKey[q] = k; candIdx[q] = (unsigned)(n4 * 4 + threadIdx.x); }
            }
        }
    }

#define PROC(vv, inb, ii)                                                            \
        if (inb) {                                                                   \
            unsigned kk, bb = (unsigned)((ii) * 4);                                  \
            kk = f2key((vv).x);                                                      \
            if (kk >= L) { unsigned p = atomicAdd(&sCnt, 1u);                        \
                if (p < CAND_LDS) { sKey[p] = kk; sIdx[p] = bb; }                    \
                else { unsigned q = atomicAdd(candCount, 1u);                        \
                       if (q < capC) { candKey[q] = kk; candIdx[q] = bb; } } }       \
            kk = f2key((vv).y);                                                      \
            if (kk >= L) { unsigned p = atomicAdd(&sCnt, 1u);                        \
                if (p < CAND_LDS) { sKey[p] = kk; sIdx[p] = bb + 1; }                \
                else { unsigned q = atomicAdd(candCount, 1u);                        \
                       if (q < capC) { candKey[q] = kk; candIdx[q] = bb + 1; } } }   \
            kk = f2key((vv).z);                                                      \
            if (kk >= L) { unsigned p = atomicAdd(&sCnt, 1u);                        \
                if (p < CAND_LDS) { sKey[p] = kk; sIdx[p] = bb + 2; }                \
                else { unsigned q = atomicAdd(candCount, 1u);                        \
                       if (q < capC) { candKey[q] = kk; candIdx[q] = bb + 2; } } }   \
            kk = f2key((vv).w);                                                      \
            if (kk >= L) { unsigned p = atomicAdd(&sCnt, 1u);                        \
                if (p < CAND_LDS) { sKey[p] = kk; sIdx[p] = bb + 3; }                \
                else { unsigned q = atomicAdd(candCount, 1u);                        \
                       if (q < capC) { candKey[q] = kk; candIdx[q] = bb + 3; } } }   \
        }

    long tiles = (n4 + 2047) >> 11;   // 2048 float4 per tile
    for (long tile = blockIdx.x; tile < tiles; tile += gridDim.x) {
        long base = tile << 11;
        long i0 = base + threadIdx.x;
        float4 v[8];
        long  ii[8];
        bool  in[8];
        #pragma unroll
        for (int j = 0; j < 8; j++) {
            ii[j] = i0 + (long)j * 256;
            in[j] = ii[j] < n4;
            if (in[j]) v[j] = x4[ii[j]];
        }
        #pragma unroll
        for (int j = 0; j < 8; j++) {
            PROC(v[j], in[j], ii[j])
        }
    }
#undef PROC
    __syncthreads();
    unsigned cnt = sCnt; if (cnt > CAND_LDS) cnt = CAND_LDS;
    if (threadIdx.x == 0) sBase = atomicAdd(candCount, cnt);
    __syncthreads();
    unsigned bp = sBase;
    for (unsigned i = threadIdx.x; i < cnt; i += 256) {
        unsigned q = bp + i;
        if (q < capC) { candKey[q] = sKey[i]; candIdx[q] = sIdx[i]; }
    }
}

// ---- fused finalize: exact T + tie-break + bucket sort + emit -----------
__global__ __launch_bounds__(1024) void k_final(const unsigned* __restrict__ candKey,
                                                const unsigned* __restrict__ candIdx,
                                                unsigned* __restrict__ ctrl, unsigned capC,
                                                unsigned* __restrict__ selKey,
                                                unsigned* __restrict__ selIdx,
                                                unsigned* __restrict__ selKeyS,
                                                unsigned* __restrict__ selIdxS,
                                                float* __restrict__ out, long n, int bshift) {
    __shared__ unsigned h[NB_BUCKET * 2];   // 32 KB
    __shared__ unsigned part[1024];
    __shared__ unsigned part2[32];
    __shared__ unsigned res[2];
    __shared__ unsigned sScalar;
    const int t = threadIdx.x;
    const int lane = t & 63;
    unsigned Nc = ctrl[0]; if (Nc > capC) Nc = capC;
    unsigned L = ctrl[1];

    // --- max key ---
    unsigned mk = 0;
    for (unsigned i = t; i < Nc; i += 1024) { unsigned k = candKey[i]; if (k > mk) mk = k; }
    part[t] = mk;
    __syncthreads();
    if (t < 32) { unsigned m = 0; for (int j = 0; j < 32; j++) { unsigned v = part[t * 32 + j]; if (v > m) m = v; } part2[t] = m; }
    __syncthreads();
    if (t == 0) { unsigned m = 0; for (int j = 0; j < 32; j++) if (part2[j] > m) m = part2[j]; sScalar = m; }
    __syncthreads();
    unsigned maxK = sScalar;

    // --- iterative radix-select: K_TOP-th from top ---
    unsigned lo = L, target = K_TOP;
    unsigned range = maxK - lo;
    int shift = 0;
    while ((range >> shift) >= NBIN) shift++;
    for (;;) {
        int nb = (int)(range >> shift) + 1;
        for (int i = t; i < nb; i += 1024) h[i] = 0;
        __syncthreads();
        for (unsigned i = t; i < Nc; i += 1024) {
            unsigned d = candKey[i] - lo;
            if (d <= range) atomicAdd(&h[d >> shift], 1u);
        }
        __syncthreads();
        int ng = (nb + 31) >> 5;
        if (t < ng) {
            unsigned s = 0; int b0 = t * 32, e = b0 + 32; if (e > nb) e = nb;
            for (int j = b0; j < e; j++) s += h[j];
            part[t] = s;
        }
        __syncthreads();
        if (t == 0) {
            unsigned cum = 0; int g = ng - 1;
            for (; g > 0; g--) { if (cum + part[g] >= target) break; cum += part[g]; }
            int hi2 = g * 32 + 31; if (hi2 > nb - 1) hi2 = nb - 1;
            int b = hi2;
            for (; b > g * 32; b--) { if (cum + h[b] >= target) break; cum += h[b]; }
            res[0] = (unsigned)b; res[1] = target - cum;
        }
        __syncthreads();
        lo += res[0] << shift; target = res[1];
        if (shift == 0) break;
        range = (1u << shift) - 1;
        shift = (shift > 11) ? shift - 11 : 0;
    }
    unsigned T = lo, R = target;

    // --- count equal keys (tree reduce, no serialized atomics) ---
    {
        unsigned loc = 0;
        for (unsigned i = t; i < Nc; i += 1024) loc += (candKey[i] == T) ? 1u : 0u;
        part[t] = loc;
        __syncthreads();
        if (t < 32) { unsigned s = 0; for (int j = 0; j < 32; j++) s += part[t * 32 + j]; part2[t] = s; }
        __syncthreads();
        if (t == 0) { unsigned s = 0; for (int j = 0; j < 32; j++) s += part2[j]; sScalar = s; }
        __syncthreads();
    }
    unsigned cntEq = sScalar;
    unsigned idxCut = 0xFFFFFFFFu;
    if (cntEq != R) {  // uniform branch
        unsigned lo2 = 0, tgt = R;
        unsigned range2 = (unsigned)(n - 1);
        int sh = 0;
        while ((range2 >> sh) >= NBIN) sh++;
        for (;;) {
            int nb = (int)(range2 >> sh) + 1;
            for (int i = t; i < nb; i += 1024) h[i] = 0;
            __syncthreads();
            for (unsigned i = t; i < Nc; i += 1024)
                if (candKey[i] == T) {
                    unsigned d = candIdx[i] - lo2;
                    if (d <= range2) atomicAdd(&h[d >> sh], 1u);
                }
            __syncthreads();
            int ng = (nb + 31) >> 5;
            if (t < ng) {
                unsigned s = 0; int b0 = t * 32, e = b0 + 32; if (e > nb) e = nb;
                for (int j = b0; j < e; j++) s += h[j];
                part[t] = s;
            }
            __syncthreads();
            if (t == 0) {
                unsigned cum = 0; int g = 0;
                for (; g < ng - 1; g++) { if (cum + part[g] >= tgt) break; cum += part[g]; }
                int b = g * 32; int hi2 = g * 32 + 31; if (hi2 > nb - 1) hi2 = nb - 1;
                for (; b < hi2; b++) { if (cum + h[b] >= tgt) break; cum += h[b]; }
                res[0] = (unsigned)b; res[1] = tgt - cum;
            }
            __syncthreads();
            lo2 += res[0] << sh; tgt = res[1];
            if (sh == 0) break;
            range2 = (1u << sh) - 1;
            sh = (sh > 11) ? sh - 11 : 0;
        }
        idxCut = lo2;
    }
    __syncthreads();

    // --- select exactly K via wave-aggregated append (1 atomic per wave) ---
    for (int i = t; i < NB_BUCKET; i += 1024) h[i] = 0;
    if (t == 0) sScalar = 0;
    __syncthreads();
    for (unsigned i = t; i < Nc; i += 1024) {
        unsigned k = candKey[i]; unsigned id = candIdx[i];
        bool sel = (k > T) || (k == T && id <= idxCut);
        unsigned long long m = __ballot(sel);
        if (m) {   // wave-uniform
            int leader = (int)__ffsll((unsigned long long)m) - 1;
            unsigned base = 0;
            if (lane == leader) base = atomicAdd(&sScalar, (unsigned)__popcll(m));
            base = __shfl(base, leader);
            if (sel) {
                unsigned p = base + (unsigned)__popcll(m & ((1ull << lane) - 1ull));
                if (p < K_TOP) {
                    selKey[p] = k; selIdx[p] = id;
                    atomicAdd(&h[id >> bshift], 1u);
                }
            }
        }
    }
    __syncthreads();
    unsigned nSel = sScalar; if (nSel > K_TOP) nSel = K_TOP;

    // --- exclusive scan of bucket counts ---
    unsigned* bc = h;
    unsigned* bs = h + NB_BUCKET;
    { unsigned s = 0; for (int j = 0; j < 4; j++) s += bc[t * 4 + j]; part[t] = s; }
    __syncthreads();
    if (t < 32) { unsigned s = 0; for (int j = 0; j < 32; j++) s += part[t * 32 + j]; part2[t] = s; }
    __syncthreads();
    if (t == 0) { unsigned run = 0; for (int j = 0; j < 32; j++) { unsigned v = part2[j]; part2[j] = run; run += v; } }
    __syncthreads();
    if (t < 32) { unsigned run = part2[t]; for (int j = 0; j < 32; j++) { int id2 = t * 32 + j; unsigned v = part[id2]; part[id2] = run; run += v; } }
    __syncthreads();
    { unsigned run = part[t]; for (int j = 0; j < 4; j++) { bs[t * 4 + j] = run; run += bc[t * 4 + j]; } }
    __syncthreads();

    // --- scatter into bucket order (bs becomes cursor) ---
    for (unsigned g = t; g < nSel; g += 1024) {
        unsigned id = selIdx[g];
        unsigned b = id >> bshift;
        unsigned p = atomicAdd(&bs[b], 1u);
        if (p < K_TOP) { selKeyS[p] = selKey[g]; selIdxS[p] = id; }
    }
    __syncthreads();

    // --- per-bucket insertion sort by idx + emit ---
    for (int j = 0; j < 4; j++) {
        int b = t * 4 + j;
        unsigned cnt = bc[b];
        if (!cnt) continue;
        unsigned s = bs[b] - cnt;
        for (unsigned i = 0; i < cnt; i++) {
            unsigned mi = i, mv = selIdxS[s + i];
            for (unsigned q = i + 1; q < cnt; q++) {
                unsigned v = selIdxS[s + q];
                if (v < mv) { mv = v; mi = q; }
            }
            if (mi != i) {
                unsigned ti = selIdxS[s + i]; selIdxS[s + i] = selIdxS[s + mi]; selIdxS[s + mi] = ti;
                unsigned tk = selKeyS[s + i]; selKeyS[s + i] = selKeyS[s + mi]; selKeyS[s + mi] = tk;
            }
            out[s + i] = key2f(selKeyS[s + i]);
        }
    }
}

// ---- host launch --------------------------------------------------------
// ws words: hist[0..2047], ctrl[2048..2055], selKey[2056..7055], selIdx[7056..12055],
//           selKeyS[12056..17055], selIdxS[17056..22055], cand arrays from 24576.
extern "C" void kernel_launch(void* const* d_in, const int* in_sizes, int n_in,
                              void* d_out, int out_size, void* d_ws, size_t ws_size,
                              hipStream_t stream) {
    const float* x = (const float*)d_in[0];
    long n = in_sizes[0];
    float* out = (float*)d_out;
    unsigned* w = (unsigned*)d_ws;

    unsigned* hist    = w;
    unsigned* ctrl    = w + 2048;
    unsigned* selKey  = w + 2056;
    unsigned* selIdx  = w + 7056;
    unsigned* selKeyS = w + 12056;
    unsigned* selIdxS = w + 17056;
    const size_t CAND_BASE = 24576;
    size_t words = ws_size / 4;
    unsigned capC = 0;
    if (words > CAND_BASE + 64) {
        size_t c = (words - CAND_BASE) / 2;
        if (c > (size_t)(4u << 20)) c = (size_t)(4u << 20);
        capC = (unsigned)c;
    }
    unsigned* candKey = w + CAND_BASE;
    unsigned* candIdx = candKey + capC;

    int bshift = 0;
    while (((n - 1) >> bshift) >= NB_BUCKET) bshift++;

    hipMemsetAsync(d_ws, 0, 2056u * 4u + 32u, stream);

    long n4 = n / 4;
    k_sample<<<256, 256, 0, stream>>>((const float4*)x, n4, hist, ctrl);
    k_compact<<<2048, 256, 0, stream>>>((const float4*)x, n4, n, x, ctrl,
                                        candKey, candIdx, capC);
    k_final<<<1, 1024, 0, stream>>>(candKey, candIdx, ctrl, capC,
                                    selKey, selIdx, selKeyS, selIdxS, out, n, bshift);
}

// Round 6
// 349.251 us; speedup vs baseline: 1.0752x; 1.0752x over previous
//
#include <hip/hip_runtime.h>

#define K_TOP 5000
#define NBIN 2048
#define CAND_LDS 1024
#define NB_BUCKET 4096
#define CAND_STAGE 12288     // staged candidate keys in LDS (48 KB)
#define TARGET_SAMPLED 94u   // ~12000 true candidates at 1/128 sampling

// ---- order-preserving float<->key mapping -------------------------------
__device__ __forceinline__ unsigned f2key(float f) {
    unsigned u = __float_as_uint(f);
    return (u & 0x80000000u) ? ~u : (u | 0x80000000u);
}
__device__ __forceinline__ float key2f(unsigned k) {
    unsigned u = (k & 0x80000000u) ? (k ^ 0x80000000u) : ~k;
    return __uint_as_float(u);
}

// ---- sampled histogram (1/128) + fused last-block threshold pick --------
// ctrl: [0]=candCount [1]=L [4]=done-counter
__global__ __launch_bounds__(256) void k_sample(const float4* __restrict__ x4, long n4,
                                                unsigned* __restrict__ hist,
                                                unsigned* __restrict__ ctrl) {
    __shared__ unsigned lh[NBIN];
    __shared__ unsigned gs[64];
    __shared__ unsigned lastFlag;
    for (int i = threadIdx.x; i < NBIN; i += 256) lh[i] = 0;
    __syncthreads();
    int wave = threadIdx.x >> 6;
    int lane = threadIdx.x & 63;
    long gw = (long)blockIdx.x * 4 + wave;
    long totW = (long)gridDim.x * 4;
    long nChunk = (n4 + 8191) / 8192;
    for (long c = gw; c < nChunk; c += totW) {
        long i = c * 8192 + lane;
        if (i < n4) {
            float4 v = x4[i];
            atomicAdd(&lh[f2key(v.x) >> 21], 1u);
            atomicAdd(&lh[f2key(v.y) >> 21], 1u);
            atomicAdd(&lh[f2key(v.z) >> 21], 1u);
            atomicAdd(&lh[f2key(v.w) >> 21], 1u);
        }
    }
    __syncthreads();
    for (int i = threadIdx.x; i < NBIN; i += 256) {
        unsigned c = lh[i];
        if (c) atomicAdd(&hist[i], c);
    }
    // ---- last block computes conservative threshold L (saves a launch) ----
    __threadfence();
    if (threadIdx.x == 0)
        lastFlag = (atomicAdd(&ctrl[4], 1u) == gridDim.x - 1) ? 1u : 0u;
    __syncthreads();
    if (!lastFlag) return;
    __threadfence();
    for (int i = threadIdx.x; i < NBIN; i += 256)
        lh[i] = __hip_atomic_load(&hist[i], __ATOMIC_RELAXED, __HIP_MEMORY_SCOPE_AGENT);
    __syncthreads();
    int t = threadIdx.x;
    if (t < 64) {
        unsigned s = 0;
        for (int j = 0; j < 32; j++) s += lh[t * 32 + j];
        gs[t] = s;
    }
    __syncthreads();
    if (t == 0) {
        unsigned cum = 0;
        int g = 63;
        for (; g > 0; g--) { if (cum + gs[g] >= TARGET_SAMPLED) break; cum += gs[g]; }
        int b = g * 32 + 31;
        for (; b > g * 32; b--) { if (cum + lh[b] >= TARGET_SAMPLED) break; cum += lh[b]; }
        ctrl[1] = ((unsigned)b) << 21;
    }
}

// ---- full pass: compact candidates (key >= L), LDS-staged ---------------
// 8x float4 per thread per tile: 128 B in flight/thread for latency hiding.
__global__ __launch_bounds__(256) void k_compact(const float4* __restrict__ x4, long n4,
                                                 long n, const float* __restrict__ x,
                                                 unsigned* __restrict__ ctrl,
                                                 unsigned* __restrict__ candKey,
                                                 unsigned* __restrict__ candIdx,
                                                 unsigned capC) {
    __shared__ unsigned sKey[CAND_LDS], sIdx[CAND_LDS];
    __shared__ unsigned sCnt, sBase;
    if (threadIdx.x == 0) sCnt = 0;
    __syncthreads();
    unsigned L = ctrl[1];
    unsigned* candCount = &ctrl[0];

    // tail (n % 4) handled by block 0
    int tail = (int)(n & 3);
    if (blockIdx.x == 0 && threadIdx.x < tail) {
        unsigned k = f2key(x[n4 * 4 + threadIdx.x]);
        if (k >= L) {
            unsigned p = atomicAdd(&sCnt, 1u);
            if (p < CAND_LDS) { sKey[p] = k; sIdx[p] = (unsigned)(n4 * 4 + threadIdx.x); }
            else {
                unsigned q = atomicAdd(candCount, 1u);
                if (q < capC) { candKey[q] = k; candIdx[q] = (unsigned)(n4 * 4 + threadIdx.x); }
            }
        }
    }

#define PROC(vv, inb, ii)                                                            \
        if (inb) {                                                                   \
            unsigned kk, bb = (unsigned)((ii) * 4);                                  \
            kk = f2key((vv).x);                                                      \
            if (kk >= L) { unsigned p = atomicAdd(&sCnt, 1u);                        \
                if (p < CAND_LDS) { sKey[p] = kk; sIdx[p] = bb; }                    \
                else { unsigned q = atomicAdd(candCount, 1u);                        \
                       if (q < capC) { candKey[q] = kk; candIdx[q] = bb; } } }       \
            kk = f2key((vv).y);                                                      \
            if (kk >= L) { unsigned p = atomicAdd(&sCnt, 1u);                        \
                if (p < CAND_LDS) { sKey[p] = kk; sIdx[p] = bb + 1; }                \
                else { unsigned q = atomicAdd(candCount, 1u);                        \
                       if (q < capC) { candKey[q] = kk; candIdx[q] = bb + 1; } } }   \
            kk = f2key((vv).z);                                                      \
            if (kk >= L) { unsigned p = atomicAdd(&sCnt, 1u);                        \
                if (p < CAND_LDS) { sKey[p] = kk; sIdx[p] = bb + 2; }                \
                else { unsigned q = atomicAdd(candCount, 1u);                        \
                       if (q < capC) { candKey[q] = kk; candIdx[q] = bb + 2; } } }   \
            kk = f2key((vv).w);                                                      \
            if (kk >= L) { unsigned p = atomicAdd(&sCnt, 1u);                        \
                if (p < CAND_LDS) { sKey[p] = kk; sIdx[p] = bb + 3; }                \
                else { unsigned q = atomicAdd(candCount, 1u);                        \
                       if (q < capC) { candKey[q] = kk; candIdx[q] = bb + 3; } } }   \
        }

    long tiles = (n4 + 2047) >> 11;   // 2048 float4 per tile
    for (long tile = blockIdx.x; tile < tiles; tile += gridDim.x) {
        long base = tile << 11;
        long i0 = base + threadIdx.x;
        float4 v[8];
        long  ii[8];
        bool  in[8];
        #pragma unroll
        for (int j = 0; j < 8; j++) {
            ii[j] = i0 + (long)j * 256;
            in[j] = ii[j] < n4;
            if (in[j]) v[j] = x4[ii[j]];
        }
        #pragma unroll
        for (int j = 0; j < 8; j++) {
            PROC(v[j], in[j], ii[j])
        }
    }
#undef PROC
    __syncthreads();
    unsigned cnt = sCnt; if (cnt > CAND_LDS) cnt = CAND_LDS;
    if (threadIdx.x == 0) sBase = atomicAdd(candCount, cnt);
    __syncthreads();
    unsigned bp = sBase;
    for (unsigned i = threadIdx.x; i < cnt; i += 256) {
        unsigned q = bp + i;
        if (q < capC) { candKey[q] = sKey[i]; candIdx[q] = sIdx[i]; }
    }
}

// ---- fused finalize: exact T + tie-break + bucket sort + emit -----------
// All repeated passes run against LDS-staged keys; selected set and the
// bucket-sorted output live entirely in LDS (123 KiB total static LDS).
__global__ __launch_bounds__(1024) void k_final(const unsigned* __restrict__ candKey,
                                                const unsigned* __restrict__ candIdx,
                                                unsigned* __restrict__ ctrl, unsigned capC,
                                                unsigned* __restrict__ selKey,
                                                unsigned* __restrict__ selIdx,
                                                unsigned* __restrict__ selKeyS,
                                                unsigned* __restrict__ selIdxS,
                                                float* __restrict__ out, long n, int bshift) {
    __shared__ unsigned cK[CAND_STAGE];     // 48 KB staged keys; reused post-select
    __shared__ unsigned h[NB_BUCKET * 2];   // 32 KB
    __shared__ unsigned selL[K_TOP];        // 20 KB selected keys
    __shared__ unsigned selIL[K_TOP];       // 20 KB selected idx
    __shared__ unsigned part[1024];
    __shared__ unsigned part2[32];
    __shared__ unsigned res[2];
    __shared__ unsigned sScalar;
    const int t = threadIdx.x;
    const int lane = t & 63;
    unsigned Nc = ctrl[0]; if (Nc > capC) Nc = capC;
    unsigned L = ctrl[1];
    unsigned ns = (Nc < CAND_STAGE) ? Nc : CAND_STAGE;

    // --- stage keys into LDS (overflow beyond CAND_STAGE stays global) ---
    for (unsigned i = t; i < ns; i += 1024) cK[i] = candKey[i];
    __syncthreads();

    // --- max key ---
    unsigned mk = 0;
    for (unsigned i = t; i < ns; i += 1024) { unsigned k = cK[i]; if (k > mk) mk = k; }
    for (unsigned i = ns + t; i < Nc; i += 1024) { unsigned k = candKey[i]; if (k > mk) mk = k; }
    part[t] = mk;
    __syncthreads();
    if (t < 32) { unsigned m = 0; for (int j = 0; j < 32; j++) { unsigned v = part[t * 32 + j]; if (v > m) m = v; } part2[t] = m; }
    __syncthreads();
    if (t == 0) { unsigned m = 0; for (int j = 0; j < 32; j++) if (part2[j] > m) m = part2[j]; sScalar = m; }
    __syncthreads();
    unsigned maxK = sScalar;

    // --- iterative radix-select: K_TOP-th from top ---
    unsigned lo = L, target = K_TOP;
    unsigned range = maxK - lo;
    int shift = 0;
    while ((range >> shift) >= NBIN) shift++;
    for (;;) {
        int nb = (int)(range >> shift) + 1;
        for (int i = t; i < nb; i += 1024) h[i] = 0;
        __syncthreads();
        for (unsigned i = t; i < ns; i += 1024) {
            unsigned d = cK[i] - lo;
            if (d <= range) atomicAdd(&h[d >> shift], 1u);
        }
        for (unsigned i = ns + t; i < Nc; i += 1024) {
            unsigned d = candKey[i] - lo;
            if (d <= range) atomicAdd(&h[d >> shift], 1u);
        }
        __syncthreads();
        int ng = (nb + 31) >> 5;
        if (t < ng) {
            unsigned s = 0; int b0 = t * 32, e = b0 + 32; if (e > nb) e = nb;
            for (int j = b0; j < e; j++) s += h[j];
            part[t] = s;
        }
        __syncthreads();
        if (t == 0) {
            unsigned cum = 0; int g = ng - 1;
            for (; g > 0; g--) { if (cum + part[g] >= target) break; cum += part[g]; }
            int hi2 = g * 32 + 31; if (hi2 > nb - 1) hi2 = nb - 1;
            int b = hi2;
            for (; b > g * 32; b--) { if (cum + h[b] >= target) break; cum += h[b]; }
            res[0] = (unsigned)b; res[1] = target - cum;
        }
        __syncthreads();
        lo += res[0] << shift; target = res[1];
        if (shift == 0) break;
        range = (1u << shift) - 1;
        shift = (shift > 11) ? shift - 11 : 0;
    }
    unsigned T = lo, R = target;

    // --- count equal keys (tree reduce) ---
    {
        unsigned loc = 0;
        for (unsigned i = t; i < ns; i += 1024) loc += (cK[i] == T) ? 1u : 0u;
        for (unsigned i = ns + t; i < Nc; i += 1024) loc += (candKey[i] == T) ? 1u : 0u;
        part[t] = loc;
        __syncthreads();
        if (t < 32) { unsigned s = 0; for (int j = 0; j < 32; j++) s += part[t * 32 + j]; part2[t] = s; }
        __syncthreads();
        if (t == 0) { unsigned s = 0; for (int j = 0; j < 32; j++) s += part2[j]; sScalar = s; }
        __syncthreads();
    }
    unsigned cntEq = sScalar;
    unsigned idxCut = 0xFFFFFFFFu;
    if (cntEq != R) {  // uniform branch (tie-break on original index)
        unsigned lo2 = 0, tgt = R;
        unsigned range2 = (unsigned)(n - 1);
        int sh = 0;
        while ((range2 >> sh) >= NBIN) sh++;
        for (;;) {
            int nb = (int)(range2 >> sh) + 1;
            for (int i = t; i < nb; i += 1024) h[i] = 0;
            __syncthreads();
            for (unsigned i = t; i < ns; i += 1024)
                if (cK[i] == T) {
                    unsigned d = candIdx[i] - lo2;
                    if (d <= range2) atomicAdd(&h[d >> sh], 1u);
                }
            for (unsigned i = ns + t; i < Nc; i += 1024)
                if (candKey[i] == T) {
                    unsigned d = candIdx[i] - lo2;
                    if (d <= range2) atomicAdd(&h[d >> sh], 1u);
                }
            __syncthreads();
            int ng = (nb + 31) >> 5;
            if (t < ng) {
                unsigned s = 0; int b0 = t * 32, e = b0 + 32; if (e > nb) e = nb;
                for (int j = b0; j < e; j++) s += h[j];
                part[t] = s;
            }
            __syncthreads();
            if (t == 0) {
                unsigned cum = 0; int g = 0;
                for (; g < ng - 1; g++) { if (cum + part[g] >= tgt) break; cum += part[g]; }
                int b = g * 32; int hi2 = g * 32 + 31; if (hi2 > nb - 1) hi2 = nb - 1;
                for (; b < hi2; b++) { if (cum + h[b] >= tgt) break; cum += h[b]; }
                res[0] = (unsigned)b; res[1] = tgt - cum;
            }
            __syncthreads();
            lo2 += res[0] << sh; tgt = res[1];
            if (sh == 0) break;
            range2 = (1u << sh) - 1;
            sh = (sh > 11) ? sh - 11 : 0;
        }
        idxCut = lo2;
    }
    __syncthreads();

    // --- select exactly K into LDS (wave-aggregated append) ---
    for (int i = t; i < NB_BUCKET; i += 1024) h[i] = 0;
    if (t == 0) sScalar = 0;
    __syncthreads();
    for (unsigned i = t; i < Nc; i += 1024) {
        unsigned k = (i < ns) ? cK[i] : candKey[i];
        unsigned id = candIdx[i];
        bool sel = (k > T) || (k == T && id <= idxCut);
        unsigned long long m = __ballot(sel);
        if (m) {   // wave-uniform
            int leader = (int)__ffsll((unsigned long long)m) - 1;
            unsigned base = 0;
            if (lane == leader) base = atomicAdd(&sScalar, (unsigned)__popcll(m));
            base = __shfl(base, leader);
            if (sel) {
                unsigned p = base + (unsigned)__popcll(m & ((1ull << lane) - 1ull));
                if (p < K_TOP) {
                    selL[p] = k; selIL[p] = id;
                    atomicAdd(&h[id >> bshift], 1u);
                }
            }
        }
    }
    __syncthreads();
    unsigned nSel = sScalar; if (nSel > K_TOP) nSel = K_TOP;

    // --- exclusive scan of bucket counts ---
    unsigned* bc = h;
    unsigned* bs = h + NB_BUCKET;
    { unsigned s = 0; for (int j = 0; j < 4; j++) s += bc[t * 4 + j]; part[t] = s; }
    __syncthreads();
    if (t < 32) { unsigned s = 0; for (int j = 0; j < 32; j++) s += part[t * 32 + j]; part2[t] = s; }
    __syncthreads();
    if (t == 0) { unsigned run = 0; for (int j = 0; j < 32; j++) { unsigned v = part2[j]; part2[j] = run; run += v; } }
    __syncthreads();
    if (t < 32) { unsigned run = part2[t]; for (int j = 0; j < 32; j++) { int id2 = t * 32 + j; unsigned v = part[id2]; part[id2] = run; run += v; } }
    __syncthreads();
    { unsigned run = part[t]; for (int j = 0; j < 4; j++) { bs[t * 4 + j] = run; run += bc[t * 4 + j]; } }
    __syncthreads();

    // --- scatter into bucket order; cK region is dead, reuse it ----------
    unsigned* sKeyS = cK;            // 5000 words
    unsigned* sIdxS = cK + K_TOP;    // 5000 words (10000 <= CAND_STAGE)
    for (unsigned g = t; g < nSel; g += 1024) {
        unsigned id = selIL[g];
        unsigned b = id >> bshift;
        unsigned p = atomicAdd(&bs[b], 1u);
        if (p < K_TOP) { sKeyS[p] = selL[g]; sIdxS[p] = id; }
    }
    __syncthreads();

    // --- per-bucket insertion sort by idx (all LDS) + emit ---
    for (int j = 0; j < 4; j++) {
        int b = t * 4 + j;
        unsigned cnt = bc[b];
        if (!cnt) continue;
        unsigned s = bs[b] - cnt;
        for (unsigned i = 0; i < cnt; i++) {
            unsigned mi = i, mv = sIdxS[s + i];
            for (unsigned q = i + 1; q < cnt; q++) {
                unsigned v = sIdxS[s + q];
                if (v < mv) { mv = v; mi = q; }
            }
            if (mi != i) {
                unsigned ti = sIdxS[s + i]; sIdxS[s + i] = sIdxS[s + mi]; sIdxS[s + mi] = ti;
                unsigned tk = sKeyS[s + i]; sKeyS[s + i] = sKeyS[s + mi]; sKeyS[s + mi] = tk;
            }
            out[s + i] = key2f(sKeyS[s + i]);
        }
    }
}

// ---- host launch --------------------------------------------------------
// ws words: hist[0..2047], ctrl[2048..2055], selKey[2056..7055], selIdx[7056..12055],
//           selKeyS[12056..17055], selIdxS[17056..22055], cand arrays from 24576.
extern "C" void kernel_launch(void* const* d_in, const int* in_sizes, int n_in,
                              void* d_out, int out_size, void* d_ws, size_t ws_size,
                              hipStream_t stream) {
    const float* x = (const float*)d_in[0];
    long n = in_sizes[0];
    float* out = (float*)d_out;
    unsigned* w = (unsigned*)d_ws;

    unsigned* hist    = w;
    unsigned* ctrl    = w + 2048;
    unsigned* selKey  = w + 2056;
    unsigned* selIdx  = w + 7056;
    unsigned* selKeyS = w + 12056;
    unsigned* selIdxS = w + 17056;
    const size_t CAND_BASE = 24576;
    size_t words = ws_size / 4;
    unsigned capC = 0;
    if (words > CAND_BASE + 64) {
        size_t c = (words - CAND_BASE) / 2;
        if (c > (size_t)(4u << 20)) c = (size_t)(4u << 20);
        capC = (unsigned)c;
    }
    unsigned* candKey = w + CAND_BASE;
    unsigned* candIdx = candKey + capC;

    int bshift = 0;
    while (((n - 1) >> bshift) >= NB_BUCKET) bshift++;

    hipMemsetAsync(d_ws, 0, 2056u * 4u + 32u, stream);

    long n4 = n / 4;
    k_sample<<<256, 256, 0, stream>>>((const float4*)x, n4, hist, ctrl);
    k_compact<<<2048, 256, 0, stream>>>((const float4*)x, n4, n, x, ctrl,
                                        candKey, candIdx, capC);
    k_final<<<1, 1024, 0, stream>>>(candKey, candIdx, ctrl, capC,
                                    selKey, selIdx, selKeyS, selIdxS, out, n, bshift);
}